// Round 7
// baseline (2309.590 us; speedup 1.0000x reference)
//
#include <hip/hip_runtime.h>
#include <cstdint>
#include <cstddef>

// Problem: B=64, T=512, I=128, H=256, 4H=1024, C=3. All fp32 in/out.
typedef _Float16 half2_t __attribute__((ext_vector_type(2)));
typedef _Float16 half8_t __attribute__((ext_vector_type(8)));
typedef float f32x4 __attribute__((ext_vector_type(4)));

static __device__ __forceinline__ float fdot2(half2_t a, half2_t b, float c) {
    return __builtin_amdgcn_fdot2(a, b, c, false);
}
static __device__ __forceinline__ half2_t h2(unsigned int u) {
    return __builtin_bit_cast(half2_t, u);
}
static __device__ __forceinline__ float sigm(float x) {
    return 1.f / (1.f + __expf(-x));
}
static __device__ __forceinline__ float tanh_fast(float x) {
    float ax = fabsf(x);
    float e = __expf(2.f * ax);
    float r = 1.f - 2.f / (e + 1.f);
    return copysignf(r, x);
}

// ---------------------------------------------------------------------------
// prep: W_hh (1024x256 fp32) -> f16 in three regions (thread tid of the scan
// owns gate rows tid and tid+512; slice s = k columns [8s, 8s+8)):
//   WpR: s = 0..5   layout [s][row]        (persistent-register part)
//   WpL: s = 6..14  layout [s-6][row]      (LDS-staged part, 144 KB)
//   WpS: s = 15..31 layout [(t*17+u)*2+p]  t=row&511, p=row>>9, u=s-15
//        -> per scan-thread 544 B contiguous: base + imm offsets, coalesced
//           across 4-load groups via L2 line reuse.
// bias = b_ih + b_hh
// ---------------------------------------------------------------------------
__global__ __launch_bounds__(256) void prep_whh(const float* __restrict__ Whh,
                                                const float* __restrict__ bih,
                                                const float* __restrict__ bhh,
                                                uint4* __restrict__ WpR,
                                                uint4* __restrict__ WpL,
                                                uint4* __restrict__ WpS,
                                                float* __restrict__ bias) {
    int n = blockIdx.x * 256 + threadIdx.x;  // 0..32767
    if (n < 1024) bias[n] = bih[n] + bhh[n];
    int row = n & 1023;
    int s = n >> 10;  // 0..31
    union { uint4 u; _Float16 h[8]; } cv;
#pragma unroll
    for (int q = 0; q < 8; ++q) cv.h[q] = (_Float16)Whh[row * 256 + s * 8 + q];
    if (s < 6) {
        WpR[s * 1024 + row] = cv.u;
    } else if (s < 15) {
        WpL[(s - 6) * 1024 + row] = cv.u;
    } else {
        int u = s - 15, t = row & 511, p = row >> 9;
        WpS[(t * 17 + u) * 2 + p] = cv.u;
    }
}

// f32 -> f16, 4 elements/thread
__global__ __launch_bounds__(256) void cvt_f16(const float* __restrict__ in,
                                               _Float16* __restrict__ out, int n4) {
    int i = blockIdx.x * 256 + threadIdx.x;
    if (i < n4) {
        float4 v = ((const float4*)in)[i];
        union { ushort4 u; _Float16 h[4]; } cv;
        cv.h[0] = (_Float16)v.x; cv.h[1] = (_Float16)v.y;
        cv.h[2] = (_Float16)v.z; cv.h[3] = (_Float16)v.w;
        ((ushort4*)out)[i] = cv.u;
    }
}

// ---------------------------------------------------------------------------
// gemm_mfma: C[M][1024] = A[M][K](f16) * W[1024][K](f16)^T + bias, fp32 out.
// ---------------------------------------------------------------------------
__global__ __launch_bounds__(256) void gemm_mfma(const _Float16* __restrict__ A,
                                                 const _Float16* __restrict__ Bw,
                                                 const float* __restrict__ bias,
                                                 float* __restrict__ Cmat, int K) {
    __shared__ _Float16 As[64][72];
    __shared__ _Float16 Bs[64][72];
    const int tid = threadIdx.x;
    const int wave = tid >> 6, lane = tid & 63;
    const int quad = lane >> 4, l16 = lane & 15;
    const int m0 = blockIdx.x * 64, n0 = blockIdx.y * 64;
    const int sr = tid >> 2;
    const int sc = (tid & 3) * 16;

    f32x4 acc[4] = {};

    for (int k0 = 0; k0 < K; k0 += 64) {
        const uint4 a0v = *(const uint4*)(A + (size_t)(m0 + sr) * K + k0 + sc);
        const uint4 a1v = *(const uint4*)(A + (size_t)(m0 + sr) * K + k0 + sc + 8);
        const uint4 b0v = *(const uint4*)(Bw + (size_t)(n0 + sr) * K + k0 + sc);
        const uint4 b1v = *(const uint4*)(Bw + (size_t)(n0 + sr) * K + k0 + sc + 8);
        __syncthreads();
        *(uint4*)&As[sr][sc] = a0v;
        *(uint4*)&As[sr][sc + 8] = a1v;
        *(uint4*)&Bs[sr][sc] = b0v;
        *(uint4*)&Bs[sr][sc + 8] = b1v;
        __syncthreads();
#pragma unroll
        for (int kc = 0; kc < 64; kc += 32) {
            half8_t af = *(const half8_t*)&As[wave * 16 + l16][kc + quad * 8];
#pragma unroll
            for (int nb = 0; nb < 4; ++nb) {
                half8_t bf = *(const half8_t*)&Bs[nb * 16 + l16][kc + quad * 8];
                acc[nb] = __builtin_amdgcn_mfma_f32_16x16x32_f16(af, bf, acc[nb], 0, 0, 0);
            }
        }
    }
#pragma unroll
    for (int nb = 0; nb < 4; ++nb) {
#pragma unroll
        for (int i = 0; i < 4; ++i) {
            int row = m0 + wave * 16 + quad * 4 + i;
            int col = n0 + nb * 16 + l16;
            Cmat[(size_t)row * 1024 + col] = acc[nb][i] + bias[col];
        }
    }
}

// ---------------------------------------------------------------------------
// lstm_scan v7: 64 WGs x 512 thr; waves_per_eu(2,2) -> 128-VGPR grant
// (empirically the allocator lands at half the waves/EU budget; this combo
// measured 128 twice). Thread tid owns gate rows tid (i|f) and tid+512 (g|o).
// Weights per thread-pair, designed to FIT 128 VGPRs:
//   s 0..5   : 12 uint4 = 48 VGPR persistent
//   s 6..14  : 144 KB LDS (staged once)
//   s 15..31 : streamed from L2 each step (272 KB/WG), base+imm offsets,
//              4-deep rolling prefetch inside the step
// h exchange: chunks 0..14 via LDS hsh; chunks 15..31 via GLOBAL broadcast
// loads from the h buffer written last step (moves the h-broadcast off the
// LDS pipe; for layer 0 the global h write IS the history output).
// Step 0 handled outside the loop (h=0 -> gates = gx).
// ---------------------------------------------------------------------------
__global__ __attribute__((amdgpu_flat_work_group_size(512, 512),
                          amdgpu_waves_per_eu(2, 2)))
void lstm_scan(const float* __restrict__ gx,
               const uint4* __restrict__ WpR,
               const uint4* __restrict__ WpL,
               const uint4* __restrict__ WpS,
               _Float16* __restrict__ hbase,  // layer0: hist; layer1: hg scratch
               int perb,                      // elements per batch (512*256 or 256)
               int hstride) {                 // elements per step (256 or 0)
    const int b = blockIdx.x;
    const int tid = threadIdx.x;   // 0..511
    const int j = tid & 255;
    const bool isIG = tid < 256;

    __shared__ uint4 wlds[9 * 1024];  // 144 KB: s = 6..14, [s'][row]
    __shared__ _Float16 hsh[256] __attribute__((aligned(16)));
    __shared__ float exf[256], exo[256];

    // stage s=6..14 into LDS (coalesced, flat copy)
#pragma unroll
    for (int i = 0; i < 18; ++i) {
        int idx = i * 512 + tid;
        wlds[idx] = WpL[idx];
    }
    // persistent register weights: s = 0..5, rows tid and tid+512 (48 VGPR)
    uint4 rl[6], rh[6];
#pragma unroll
    for (int u = 0; u < 6; ++u) {
        rl[u] = WpR[u * 1024 + tid];
        rh[u] = WpR[u * 1024 + 512 + tid];
    }
    const uint4* wsp = WpS + (size_t)tid * 34;  // 17 slices x 2 rows

    _Float16* hb = hbase + (size_t)b * perb;
    const float* gxb = gx + (size_t)b * 512 * 1024;

    if (isIG) hsh[j] = (_Float16)0.f;
    float c = 0.f;
    float gl = gxb[tid], gh = gxb[512 + tid];          // gx for t=0
    float gl_n = gxb[1024 + tid], gh_n = gxb[1536 + tid];  // gx for t=1
    __syncthreads();  // wlds + hsh visible

    // ---- step 0: h = 0 -> gates = gx ----
    {
        float v0 = 0.f, v1 = 0.f;
        if (isIG) { v0 = sigm(gl); v1 = tanh_fast(gh); }
        else      { exf[j] = sigm(gl); exo[j] = sigm(gh); }
        gl = gl_n; gh = gh_n;
        __syncthreads();
        if (isIG) {
            const float fv = exf[j], ov = exo[j];
            c = fv * c + v0 * v1;
            const _Float16 hh = (_Float16)(ov * tanh_fast(c));
            hsh[j] = hh;
            hb[j] = hh;  // h_0 -> global (hist[t=0] or scratch)
        }
        __syncthreads();
    }

    for (int t = 1; t < 512; ++t) {
        const _Float16* rd = hb + (size_t)(t - 1) * hstride;  // h_{t-1}
        // prefetch next step's gx
        if (t < 511) {
            const float* g4 = gxb + (size_t)(t + 1) * 1024;
            gl_n = g4[tid];
            gh_n = g4[512 + tid];
        }

        // rolling 4-deep prefetch for the streamed part (slices 15..31):
        // h chunk from global broadcast, 2 w rows from WpS
        uint4 hbuf[4], wb0[4], wb1[4];
#pragma unroll
        for (int i = 0; i < 4; ++i) {
            hbuf[i] = *(const uint4*)(rd + (15 + i) * 8);
            wb0[i] = wsp[2 * i];
            wb1[i] = wsp[2 * i + 1];
        }

        const uint4* hbl = (const uint4*)hsh;
        float a0x = 0.f, a0y = 0.f, a1x = 0.f, a1y = 0.f;

        // register slices 0..5 (h from LDS chunks 0..5)
#pragma unroll
        for (int u = 0; u < 6; ++u) {
            const uint4 hv = hbl[u];
            a0x = fdot2(h2(rl[u].x), h2(hv.x), a0x);
            a0x = fdot2(h2(rl[u].y), h2(hv.y), a0x);
            a0y = fdot2(h2(rl[u].z), h2(hv.z), a0y);
            a0y = fdot2(h2(rl[u].w), h2(hv.w), a0y);
            a1x = fdot2(h2(rh[u].x), h2(hv.x), a1x);
            a1x = fdot2(h2(rh[u].y), h2(hv.y), a1x);
            a1y = fdot2(h2(rh[u].z), h2(hv.z), a1y);
            a1y = fdot2(h2(rh[u].w), h2(hv.w), a1y);
        }
        // LDS slices 6..14 (h from LDS chunks 6..14)
#pragma unroll
        for (int u = 0; u < 9; ++u) {
            const uint4 wl = wlds[u * 1024 + tid];
            const uint4 wh = wlds[u * 1024 + 512 + tid];
            const uint4 hv = hbl[6 + u];
            a0x = fdot2(h2(wl.x), h2(hv.x), a0x);
            a0x = fdot2(h2(wl.y), h2(hv.y), a0x);
            a0y = fdot2(h2(wl.z), h2(hv.z), a0y);
            a0y = fdot2(h2(wl.w), h2(hv.w), a0y);
            a1x = fdot2(h2(wh.x), h2(hv.x), a1x);
            a1x = fdot2(h2(wh.y), h2(hv.y), a1x);
            a1y = fdot2(h2(wh.z), h2(hv.z), a1y);
            a1y = fdot2(h2(wh.w), h2(hv.w), a1y);
        }
        // streamed slices 15..31: rolling prefetch, all within this step
#pragma unroll
        for (int s = 0; s < 17; ++s) {
            const uint4 hv = hbuf[s & 3];
            const uint4 wl = wb0[s & 3];
            const uint4 wh = wb1[s & 3];
            if (s + 4 < 17) {
                hbuf[s & 3] = *(const uint4*)(rd + (19 + s) * 8);
                wb0[s & 3] = wsp[2 * (s + 4)];
                wb1[s & 3] = wsp[2 * (s + 4) + 1];
            }
            a0x = fdot2(h2(wl.x), h2(hv.x), a0x);
            a0x = fdot2(h2(wl.y), h2(hv.y), a0x);
            a0y = fdot2(h2(wl.z), h2(hv.z), a0y);
            a0y = fdot2(h2(wl.w), h2(hv.w), a0y);
            a1x = fdot2(h2(wh.x), h2(hv.x), a1x);
            a1x = fdot2(h2(wh.y), h2(hv.y), a1x);
            a1y = fdot2(h2(wh.z), h2(hv.z), a1y);
            a1y = fdot2(h2(wh.w), h2(hv.w), a1y);
        }

        const float plo = a0x + a0y + gl;  // row tid   (i or f)
        const float phi = a1x + a1y + gh;  // row tid+512 (g or o)
        float v0 = 0.f, v1 = 0.f;
        if (isIG) { v0 = sigm(plo); v1 = tanh_fast(phi); }
        else      { exf[j] = sigm(plo); exo[j] = sigm(phi); }
        gl = gl_n; gh = gh_n;
        __syncthreads();  // acts visible; all hsh/global h reads retired
        if (isIG) {
            const float fv = exf[j], ov = exo[j];
            c = fv * c + v0 * v1;
            const _Float16 hh = (_Float16)(ov * tanh_fast(c));
            hsh[j] = hh;
            hb[(size_t)t * hstride + j] = hh;  // h_t -> global (drained at next barrier)
        }
        __syncthreads();  // h (LDS + global) visible for step t+1
    }
}

// ---------------------------------------------------------------------------
// fc_softmax: logits = hlast[b,:](f16) @ fc_w^T + fc_b, softmax over 3
// ---------------------------------------------------------------------------
__global__ __launch_bounds__(64) void fc_softmax(const _Float16* __restrict__ hlast,
                                                 const float* __restrict__ fcw,
                                                 const float* __restrict__ fcb,
                                                 float* __restrict__ out) {
    const int b = blockIdx.x;
    const int lane = threadIdx.x;
    const _Float16* h = hlast + (size_t)b * 256;
    float p0 = 0.f, p1 = 0.f, p2 = 0.f;
    for (int k = lane; k < 256; k += 64) {
        float hv = (float)h[k];
        p0 += hv * fcw[k];
        p1 += hv * fcw[256 + k];
        p2 += hv * fcw[512 + k];
    }
#pragma unroll
    for (int off = 32; off > 0; off >>= 1) {
        p0 += __shfl_down(p0, off);
        p1 += __shfl_down(p1, off);
        p2 += __shfl_down(p2, off);
    }
    if (lane == 0) {
        float l0 = p0 + fcb[0], l1 = p1 + fcb[1], l2 = p2 + fcb[2];
        float m = fmaxf(l0, fmaxf(l1, l2));
        float e0 = __expf(l0 - m), e1 = __expf(l1 - m), e2 = __expf(l2 - m);
        float s = 1.f / (e0 + e1 + e2);
        out[b * 3 + 0] = e0 * s;
        out[b * 3 + 1] = e1 * s;
        out[b * 3 + 2] = e2 * s;
    }
}

extern "C" void kernel_launch(void* const* d_in, const int* in_sizes, int n_in,
                              void* d_out, int out_size, void* d_ws, size_t ws_size,
                              hipStream_t stream) {
    const float* x    = (const float*)d_in[0];
    const float* Wih0 = (const float*)d_in[1];
    const float* Whh0 = (const float*)d_in[2];
    const float* bih0 = (const float*)d_in[3];
    const float* bhh0 = (const float*)d_in[4];
    const float* Wih1 = (const float*)d_in[5];
    const float* Whh1 = (const float*)d_in[6];
    const float* bih1 = (const float*)d_in[7];
    const float* bhh1 = (const float*)d_in[8];
    const float* fcw  = (const float*)d_in[9];
    const float* fcb  = (const float*)d_in[10];
    float* out = (float*)d_out;

    // workspace layout (~161 MB)
    char* ws = (char*)d_ws;
    float* gx        = (float*)ws;     ws += (size_t)32768 * 1024 * 4;  // 134.2 MB
    _Float16* h0f    = (_Float16*)ws;  ws += (size_t)32768 * 256 * 2;   // 16.8 MB (layer0 hist)
    _Float16* xh     = (_Float16*)ws;  ws += (size_t)32768 * 128 * 2;   // 8.4 MB
    _Float16* hg1    = (_Float16*)ws;  ws += (size_t)64 * 256 * 2;      // 32 KB (layer1 h scratch = hlast)
    _Float16* Wih0h  = (_Float16*)ws;  ws += (size_t)1024 * 128 * 2;    // 256 KB
    _Float16* Wih1h  = (_Float16*)ws;  ws += (size_t)1024 * 256 * 2;    // 512 KB
    uint4* WpR0      = (uint4*)ws;     ws += (size_t)6 * 1024 * 16;     // 96 KB
    uint4* WpL0      = (uint4*)ws;     ws += (size_t)9 * 1024 * 16;     // 144 KB
    uint4* WpS0      = (uint4*)ws;     ws += (size_t)17 * 1024 * 16;    // 272 KB
    uint4* WpR1      = (uint4*)ws;     ws += (size_t)6 * 1024 * 16;
    uint4* WpL1      = (uint4*)ws;     ws += (size_t)9 * 1024 * 16;
    uint4* WpS1      = (uint4*)ws;     ws += (size_t)17 * 1024 * 16;
    float* bias0     = (float*)ws;     ws += 4096;
    float* bias1     = (float*)ws;     ws += 4096;

    prep_whh<<<128, 256, 0, stream>>>(Whh0, bih0, bhh0, WpR0, WpL0, WpS0, bias0);
    prep_whh<<<128, 256, 0, stream>>>(Whh1, bih1, bhh1, WpR1, WpL1, WpS1, bias1);
    cvt_f16<<<4096, 256, 0, stream>>>(x, xh, 32768 * 128 / 4);
    cvt_f16<<<128, 256, 0, stream>>>(Wih0, Wih0h, 1024 * 128 / 4);
    cvt_f16<<<256, 256, 0, stream>>>(Wih1, Wih1h, 1024 * 256 / 4);

    // layer 0 (h history -> h0f, doubles as the per-step h exchange buffer)
    gemm_mfma<<<dim3(512, 16), 256, 0, stream>>>(xh, Wih0h, bias0, gx, 128);
    lstm_scan<<<64, 512, 0, stream>>>(gx, WpR0, WpL0, WpS0, h0f, 512 * 256, 256);

    // layer 1 (h exchange in fixed 512-B scratch per batch; hlast = hg1)
    gemm_mfma<<<dim3(512, 16), 256, 0, stream>>>(h0f, Wih1h, bias1, gx, 256);
    lstm_scan<<<64, 512, 0, stream>>>(gx, WpR1, WpL1, WpS1, hg1, 256, 0);

    fc_softmax<<<64, 64, 0, stream>>>(hg1, fcw, fcb, out);
}